// Round 7
// baseline (505.654 us; speedup 1.0000x reference)
//
#include <hip/hip_runtime.h>
#include <hip/hip_cooperative_groups.h>
#include <cstdint>
#include <cstddef>

namespace cg = cooperative_groups;

#define SCALE  0.08838834764831845f   // 128^-0.5
#define EPS_   1e-8f
#define LN_EPS_ 1e-5f

typedef unsigned short ushort_t;
typedef unsigned int uint_t;
typedef __attribute__((ext_vector_type(8))) short short8;
typedef __attribute__((ext_vector_type(4))) float f32x4;

// ---------------- workspace layout (float offsets), 19.2 MB ----------------
constexpr int OFF_GFD   = 0;        // 256   (f_w1@g_w)/DELTA  [h][2]
constexpr int OFF_CB    = 256;      // 128   f_w1@g_b + f_b1
constexpr int OFF_QB    = 384;      // 64
constexpr int OFF_SP    = 448;      // 128
constexpr int OFF_OQ    = 576;      // 16384 interleaved (off, qf*scale)
constexpr int OFF_SLOTS = 16960;    // 8192
constexpr int OFF_ZP    = 25152;    // 4096   [b][64][8]
constexpr int OFF_PP    = 29248;    // 8192   [b][64][8][2]
constexpr int OFF_UP    = 37440;    // 524288 [b][64][8][128]
constexpr int OFF_WKB   = 561728;   // bf16 [128][128] = 8192 float-slots
constexpr int OFF_WVB   = 569920;   // 8192
constexpr int OFF_FW2T  = 578112;   // f32 f_w2^T 16384
constexpr int OFF_BKT   = 594496;   // bf16 [b][128][4096] = 2097152 float-slots
constexpr int OFF_BV    = 2691648;  // bf16 [b][4096][128] = 2097152 float-slots
// end: 4788800 floats

__device__ __forceinline__ float waveReduceSum(float v) {
#pragma unroll
  for (int m = 1; m < 64; m <<= 1) v += __shfl_xor(v, m, 64);
  return v;
}
__device__ __forceinline__ float bf2f(uint_t u) { return __uint_as_float(u << 16); }
__device__ __forceinline__ ushort_t f2bf(float f) {
  uint_t u = __float_as_uint(f);
  return (ushort_t)((u + 0x7fffu + ((u >> 16) & 1u)) >> 16);
}

// half-row dot (e-range [h*64, h*64+64)), 16 independent float4 loads
__device__ __forceinline__ float halfDot(const float* __restrict__ Wrow,
                                         const float* xv, int h) {
  const float4* wr = (const float4*)Wrow + h * 16;
  const float4* xr = (const float4*)xv + h * 16;
  float4 a = {0.f, 0.f, 0.f, 0.f};
#pragma unroll
  for (int i = 0; i < 16; ++i) {
    float4 wv = wr[i], xq = xr[i];
    a.x = fmaf(wv.x, xq.x, a.x);
    a.y = fmaf(wv.y, xq.y, a.y);
    a.z = fmaf(wv.z, xq.z, a.z);
    a.w = fmaf(wv.w, xq.w, a.w);
  }
  return (a.x + a.y) + (a.z + a.w);
}

// ---------------- fold weights ----------------
__global__ __launch_bounds__(256) void kFold(
    const float* __restrict__ f_w1, const float* __restrict__ Wk,
    const float* __restrict__ Wv, const float* __restrict__ g_w,
    const float* __restrict__ g_b, const float* __restrict__ f_b1,
    const float* __restrict__ f_w2, float* __restrict__ ws) {
  int blk = blockIdx.x, tid = threadIdx.x;
  if (blk < 128) {
    int isV = blk >> 6;
    int idx = (blk & 63) * 256 + tid;           // 0..16383  (h*128+e)
    int h = idx >> 7, e = idx & 127;
    const float* Wm = isV ? Wv : Wk;
    float a = 0.f;
#pragma unroll 4
    for (int d = 0; d < 128; ++d) a = fmaf(f_w1[h * 128 + d], Wm[d * 128 + e], a);
    ((ushort_t*)(ws + (isV ? OFF_WVB : OFF_WKB)))[idx] = f2bf(a);
  } else if (blk == 128) {
    int h = tid >> 1, c = tid & 1;
    float a = 0.f;
    for (int d = 0; d < 128; ++d) a = fmaf(f_w1[h * 128 + d], g_w[d * 2 + c], a);
    ws[OFF_GFD + tid] = a * 0.2f;               // /DELTA (DELTA=5)
  } else if (blk == 129) {
    if (tid < 128) {
      float a = f_b1[tid];
      for (int d = 0; d < 128; ++d) a = fmaf(f_w1[tid * 128 + d], g_b[d], a);
      ws[OFF_CB + tid] = a;
    }
  } else {
    for (int i = tid; i < 16384; i += 256)
      ws[OFF_FW2T + (i & 127) * 128 + (i >> 7)] = f_w2[i];
  }
}

// ---------------- MFMA base GEMMs (f32 inputs cast in-register) ----------------
__global__ __launch_bounds__(256) void kBase(const float* __restrict__ inputs,
                                             float* __restrict__ ws) {
  __shared__ __align__(16) char ep[17408];      // epilogue transpose buffer
  int tid = threadIdx.x, w = tid >> 6, l = tid & 63;
  int lr = l & 15, lg = l >> 4;
  int mat = blockIdx.y;
  int rowblk = blockIdx.x * 128;
  int b = blockIdx.x >> 5;
  int nb_in_b = (blockIdx.x & 31) * 128;
  const ushort_t* Wg = (const ushort_t*)(ws + (mat ? OFF_WVB : OFF_WKB));

  short8 afrag[2][4];
#pragma unroll
  for (int rt = 0; rt < 2; ++rt)
#pragma unroll
    for (int ks = 0; ks < 4; ++ks) {
      size_t row = (size_t)rowblk + w * 32 + rt * 16 + lr;
      const float* ip = inputs + row * 128 + ks * 32 + lg * 8;
      float4 x0 = *(const float4*)ip;
      float4 x1 = *(const float4*)(ip + 4);
      short8 fr;
      fr[0] = (short)f2bf(x0.x); fr[1] = (short)f2bf(x0.y);
      fr[2] = (short)f2bf(x0.z); fr[3] = (short)f2bf(x0.w);
      fr[4] = (short)f2bf(x1.x); fr[5] = (short)f2bf(x1.y);
      fr[6] = (short)f2bf(x1.z); fr[7] = (short)f2bf(x1.w);
      afrag[rt][ks] = fr;
    }
  float gf0a[8], gf1a[8], cba[8];
#pragma unroll
  for (int ct = 0; ct < 8; ++ct) {
    int c = ct * 16 + lr;
    gf0a[ct] = ws[OFF_GFD + c * 2 + 0];
    gf1a[ct] = ws[OFF_GFD + c * 2 + 1];
    cba[ct]  = ws[OFF_CB + c];
  }
  f32x4 acc[2][8];
#pragma unroll
  for (int rt = 0; rt < 2; ++rt)
#pragma unroll
    for (int ct = 0; ct < 8; ++ct) acc[rt][ct] = (f32x4){0.f, 0.f, 0.f, 0.f};
#pragma unroll 2
  for (int ct = 0; ct < 8; ++ct) {
    short8 bfr[4];
#pragma unroll
    for (int ks = 0; ks < 4; ++ks)
      bfr[ks] = *(const short8*)(Wg + (ct * 16 + lr) * 128 + ks * 32 + lg * 8);
#pragma unroll
    for (int ks = 0; ks < 4; ++ks) {
      acc[0][ct] = __builtin_amdgcn_mfma_f32_16x16x32_bf16(afrag[0][ks], bfr[ks], acc[0][ct], 0, 0, 0);
      acc[1][ct] = __builtin_amdgcn_mfma_f32_16x16x32_bf16(afrag[1][ks], bfr[ks], acc[1][ct], 0, 0, 0);
    }
  }
  ushort_t* outK = (ushort_t*)(ws + OFF_BKT);
  ushort_t* outV = (ushort_t*)(ws + OFF_BV);
  for (int h = 0; h < 2; ++h) {
    __syncthreads();
    if ((w >> 1) == h) {
      int nl0 = (w & 1) * 32 + lg * 4;
#pragma unroll
      for (int rt = 0; rt < 2; ++rt)
#pragma unroll
        for (int ct = 0; ct < 8; ++ct) {
          int c = ct * 16 + lr;
          ushort_t pk[4];
#pragma unroll
          for (int r = 0; r < 4; ++r) {
            int n = nb_in_b + h * 64 + nl0 + rt * 16 + r;
            float gy = -1.f + (float)(n >> 6) * (2.f / 63.f);
            float gx = -1.f + (float)(n & 63) * (2.f / 63.f);
            float o = acc[rt][ct][r] + gy * gf0a[ct] + gx * gf1a[ct] + cba[ct];
            pk[r] = f2bf(o);
          }
          if (mat == 0) {
            int byte = (c * 128 + (nl0 + rt * 16) * 2) ^ ((c & 7) << 4);
            *(uint2*)(ep + byte) = make_uint2(
                (uint_t)pk[0] | ((uint_t)pk[1] << 16),
                (uint_t)pk[2] | ((uint_t)pk[3] << 16));
          } else {
            int rb = nl0 + rt * 16;
#pragma unroll
            for (int r = 0; r < 4; ++r)
              *(ushort_t*)(ep + (rb + r) * 272 + c * 2) = pk[r];
          }
        }
    }
    __syncthreads();
    if (mat == 0) {
      for (int idx = tid; idx < 1024; idx += 256) {
        int c = idx >> 3, j = idx & 7;
        uint4 v = *(const uint4*)(ep + ((c * 128 + j * 16) ^ ((c & 7) << 4)));
        *(uint4*)(outK + ((size_t)(b * 128 + c)) * 4096 + nb_in_b + h * 64 + j * 8) = v;
      }
    } else {
      for (int idx = tid; idx < 1024; idx += 256) {
        int nl = idx >> 4, j = idx & 15;
        uint4 v = *(const uint4*)(ep + nl * 272 + j * 16);
        *(uint4*)(outV + ((size_t)rowblk + h * 64 + nl) * 128 + j * 8) = v;
      }
    }
  }
}

// ---------------- shared-memory overlays ----------------
struct AttnSm {
  float2 OQl[8][128];     // 8 KB
  float tp[64][37];
  float al[64][13];
  float Ush[4][8][132];
};
struct QSm { float yl[128]; float ql[128]; float red[4]; float red2[4]; };
struct CQSm {
  float ul[128]; float xl[128]; float sl[128]; float yl[128]; float hml[128];
  float red[4]; float red2[4];
};
constexpr size_t SM_BYTES = sizeof(AttnSm);   // 37888

struct IterParams {
  const float *Wq, *f_w2, *f_b2;
  const float *wih, *whh, *bih, *bhh;
  const float *mw1, *mb1, *mw2, *mb2;
  const float *lnpg, *lnpb, *lnsg, *lnsb;
  const float *S_r, *S_s;
  float* ws;
  float* out;
};

// ---------------- phase: q projection (per b,s block; 256 thr) ----------------
__device__ void doQ(int bs, const IterParams& p, QSm& S) {
  float* ws = p.ws;
  int t = threadIdx.x, w = t >> 6, lane = t & 63;
  int d = w * 32 + (lane >> 1), h = lane & 1;
  const float* FW2T = ws + OFF_FW2T;
  float x = ws[OFF_SLOTS + bs * 128 + d];
  float m1 = waveReduceSum(h == 0 ? x : 0.f);
  float m2 = waveReduceSum(h == 0 ? x * x : 0.f);
  if (lane == 0) { S.red[w] = m1; S.red2[w] = m2; }
  __syncthreads();
  float mean = (S.red[0] + S.red[1] + S.red[2] + S.red[3]) * (1.f / 128.f);
  float var = (S.red2[0] + S.red2[1] + S.red2[2] + S.red2[3]) * (1.f / 128.f) - mean * mean;
  if (h == 0) S.yl[d] = (x - mean) * rsqrtf(var + LN_EPS_) * p.lnsg[d] + p.lnsb[d];
  __syncthreads();
  float q = halfDot(p.Wq + (size_t)d * 128, S.yl, h);
  q += __shfl_xor(q, 1, 64);
  if (h == 0) S.ql[d] = q;
  __syncthreads();
  float qv = waveReduceSum(h == 0 ? q * p.f_b2[d] : 0.f);
  if (lane == 0) S.red[w] = qv;
  float qf = halfDot(FW2T + (size_t)d * 128, S.ql, h);
  qf += __shfl_xor(qf, 1, 64);
  __syncthreads();
  if (t == 0) ws[OFF_QB + bs] = (S.red[0] + S.red[1] + S.red[2] + S.red[3]) * SCALE;
  if (h == 0) {
    float sp0 = ws[OFF_SP + bs * 2 + 0], sp1 = ws[OFF_SP + bs * 2 + 1];
    float offd = -(sp0 * ws[OFF_GFD + d * 2 + 0] + sp1 * ws[OFF_GFD + d * 2 + 1]);
    ws[OFF_OQ + (bs * 128 + d) * 2 + 0] = offd;
    ws[OFF_OQ + (bs * 128 + d) * 2 + 1] = qf * SCALE;
  }
}

// ---------------- phase: attention (per block: one b, TWO chunks) ----------------
__device__ void doAttnPair(int blk, float* __restrict__ ws, AttnSm& S) {
  int b = blk >> 5, cp = blk & 31;
  int tid = threadIdx.x, w = tid >> 6, lane = tid & 63;
  int sb = b * 8;
  for (int f = tid; f < 1024; f += 256) {
    int s = f >> 7, d = f & 127;
    S.OQl[s][d] = *(const float2*)&ws[OFF_OQ + ((sb + s) * 128 + d) * 2];
  }
  float qbl[8];
#pragma unroll
  for (int s = 0; s < 8; ++s) qbl[s] = ws[OFF_QB + sb + s];
  __syncthreads();

  for (int half = 0; half < 2; ++half) {
    int chunk = cp * 2 + half;
    // ---- phase 1: pixel-per-lane dots over this wave's d-quarter ----
    int n = chunk * 64 + lane;
    const ushort_t* kp = (const ushort_t*)(ws + OFF_BKT) +
                         (size_t)b * 524288 + (size_t)w * 32 * 4096 + n;
    float t[8];
#pragma unroll
    for (int s = 0; s < 8; ++s) t[s] = 0.f;
#pragma unroll 4
    for (int dd = 0; dd < 32; ++dd) {
      int d = w * 32 + dd;
      float kv = bf2f((uint_t)kp[(size_t)dd * 4096]);
#pragma unroll
      for (int s = 0; s < 8; ++s) {
        float2 oq = S.OQl[s][d];
        t[s] = fmaf(fmaxf(kv + oq.x, 0.f), oq.y, t[s]);
      }
    }
#pragma unroll
    for (int s = 0; s < 8; ++s) S.tp[lane][s * 4 + w] = t[s];
    __syncthreads();
    float a[8], den = 0.f;
#pragma unroll
    for (int s = 0; s < 8; ++s)
      t[s] = S.tp[lane][s * 4 + 0] + S.tp[lane][s * 4 + 1] +
             S.tp[lane][s * 4 + 2] + S.tp[lane][s * 4 + 3] + qbl[s];
    float mx = t[0];
#pragma unroll
    for (int s = 1; s < 8; ++s) mx = fmaxf(mx, t[s]);
#pragma unroll
    for (int s = 0; s < 8; ++s) { a[s] = __expf(t[s] - mx); den += a[s]; }
    float inv = 1.0f / den;
#pragma unroll
    for (int s = 0; s < 8; ++s) a[s] = fmaf(a[s], inv, EPS_);
    if (w == 0) {
      float gy = -1.f + (float)(n >> 6) * (2.f / 63.f);
      float gx = -1.f + (float)(n & 63) * (2.f / 63.f);
#pragma unroll
      for (int s = 0; s < 8; ++s) S.al[lane][s] = a[s];
#pragma unroll
      for (int s = 0; s < 8; ++s) {
        float z = waveReduceSum(a[s]);
        float p0 = waveReduceSum(a[s] * gy);
        float p1 = waveReduceSum(a[s] * gx);
        if (lane == 0) {
          ws[OFF_ZP + (b * 64 + chunk) * 8 + s] = z;
          ws[OFF_PP + ((b * 64 + chunk) * 8 + s) * 2 + 0] = p0;
          ws[OFF_PP + ((b * 64 + chunk) * 8 + s) * 2 + 1] = p1;
        }
      }
    }
    __syncthreads();

    // ---- phase 2: channel-pair-per-lane over this wave's 16 pixels ----
    int c0 = 2 * lane;
    float offv0[8], offv1[8];
#pragma unroll
    for (int s = 0; s < 8; ++s) {
      offv0[s] = S.OQl[s][c0].x;
      offv1[s] = S.OQl[s][c0 + 1].x;
    }
    float Ua0[8], Ua1[8];
#pragma unroll
    for (int s = 0; s < 8; ++s) { Ua0[s] = 0.f; Ua1[s] = 0.f; }
    const ushort_t* vp = (const ushort_t*)(ws + OFF_BV) +
                         ((size_t)(b * 4096 + chunk * 64 + w * 16)) * 128 + c0;
#pragma unroll 4
    for (int i = 0; i < 16; ++i) {
      uint_t vraw = *(const uint_t*)(vp + (size_t)i * 128);
      float v0 = bf2f(vraw & 0xffffu);
      float v1 = bf2f(vraw >> 16);
      int ii = w * 16 + i;
#pragma unroll
      for (int s = 0; s < 8; ++s) {
        float as = S.al[ii][s];
        Ua0[s] = fmaf(as, fmaxf(v0 + offv0[s], 0.f), Ua0[s]);
        Ua1[s] = fmaf(as, fmaxf(v1 + offv1[s], 0.f), Ua1[s]);
      }
    }
#pragma unroll
    for (int s = 0; s < 8; ++s)
      *(float2*)&S.Ush[w][s][c0] = make_float2(Ua0[s], Ua1[s]);
    __syncthreads();
    for (int f = tid; f < 1024; f += 256) {
      int s = f >> 7, c = f & 127;
      float v = S.Ush[0][s][c] + S.Ush[1][s][c] + S.Ush[2][s][c] + S.Ush[3][s][c];
      ws[OFF_UP + ((size_t)(b * 64 + chunk) * 8 + s) * 128 + c] = v;
    }
    __syncthreads();   // guard before next half rewrites tp/al/Ush
  }
}

// ---------------- phase: finalize + GRU + post-MLP + next-iter q (256 thr) ----------------
__device__ void doCQ(int bs, const IterParams& p, CQSm& S) {
  float* ws = p.ws;
  int b = bs >> 3, s = bs & 7;
  int t = threadIdx.x, w = t >> 6, lane = t & 63;
  int d = w * 32 + (lane >> 1), h = lane & 1;
  const float* FW2T = ws + OFF_FW2T;
  float zv = ws[OFF_ZP + (b * 64 + lane) * 8 + s];
  float2 pv = *(const float2*)&ws[OFF_PP + ((size_t)(b * 64 + lane) * 8 + s) * 2];
  float Z = waveReduceSum(zv);
  float P0 = waveReduceSum(pv.x);
  float P1 = waveReduceSum(pv.y);
  float invZ = 1.f / Z, sp0 = P0 * invZ, sp1 = P1 * invZ;
  float u = 0.f;
  const float* up = ws + OFF_UP + ((size_t)(b * 64 + h * 32) * 8 + s) * 128 + d;
#pragma unroll 8
  for (int ch = 0; ch < 32; ++ch) u += up[(size_t)ch * 1024];
  u += __shfl_xor(u, 1, 64);
  if (h == 0) { S.ul[d] = u * invZ; S.sl[d] = ws[OFF_SLOTS + bs * 128 + d]; }
  if (t == 0) { ws[OFF_SP + bs * 2 + 0] = sp0; ws[OFF_SP + bs * 2 + 1] = sp1; }
  __syncthreads();
  float xa = halfDot(p.f_w2 + (size_t)d * 128, S.ul, h);
  xa += __shfl_xor(xa, 1, 64);
  if (h == 0) S.xl[d] = xa + p.f_b2[d];
  __syncthreads();
  float ir = halfDot(p.wih + (size_t)d * 128, S.xl, h);
  float iz = halfDot(p.wih + (size_t)(128 + d) * 128, S.xl, h);
  float in_ = halfDot(p.wih + (size_t)(256 + d) * 128, S.xl, h);
  float hr = halfDot(p.whh + (size_t)d * 128, S.sl, h);
  float hz = halfDot(p.whh + (size_t)(128 + d) * 128, S.sl, h);
  float hn = halfDot(p.whh + (size_t)(256 + d) * 128, S.sl, h);
  ir += __shfl_xor(ir, 1, 64);
  iz += __shfl_xor(iz, 1, 64);
  in_ += __shfl_xor(in_, 1, 64);
  hr += __shfl_xor(hr, 1, 64);
  hz += __shfl_xor(hz, 1, 64);
  hn += __shfl_xor(hn, 1, 64);
  float hnew = 0.f;
  if (h == 0) {
    float rg = 1.f / (1.f + __expf(-(ir + p.bih[d] + hr + p.bhh[d])));
    float zg = 1.f / (1.f + __expf(-(iz + p.bih[128 + d] + hz + p.bhh[128 + d])));
    float ng = tanhf(in_ + p.bih[256 + d] + rg * (hn + p.bhh[256 + d]));
    hnew = (1.f - zg) * ng + zg * S.sl[d];
  }
  float m1 = waveReduceSum(h == 0 ? hnew : 0.f);
  float m2 = waveReduceSum(h == 0 ? hnew * hnew : 0.f);
  if (lane == 0) { S.red[w] = m1; S.red2[w] = m2; }
  __syncthreads();
  float mean = (S.red[0] + S.red[1] + S.red[2] + S.red[3]) * (1.f / 128.f);
  float var = (S.red2[0] + S.red2[1] + S.red2[2] + S.red2[3]) * (1.f / 128.f) - mean * mean;
  if (h == 0) S.yl[d] = (hnew - mean) * rsqrtf(var + LN_EPS_) * p.lnpg[d] + p.lnpb[d];
  __syncthreads();
  float hm = halfDot(p.mw1 + (size_t)d * 128, S.yl, h);
  hm += __shfl_xor(hm, 1, 64);
  if (h == 0) S.hml[d] = fmaxf(hm + p.mb1[d], 0.f);
  __syncthreads();
  float oa = halfDot(p.mw2 + (size_t)d * 128, S.hml, h);
  oa += __shfl_xor(oa, 1, 64);
  float o = 0.f;
  if (h == 0) {
    o = hnew + p.mb2[d] + oa;
    ws[OFF_SLOTS + bs * 128 + d] = o;
  }
  float n1 = waveReduceSum(h == 0 ? o : 0.f);
  float n2 = waveReduceSum(h == 0 ? o * o : 0.f);
  if (lane == 0) { S.red[w] = n1; S.red2[w] = n2; }
  __syncthreads();
  float mean2 = (S.red[0] + S.red[1] + S.red[2] + S.red[3]) * (1.f / 128.f);
  float var2 = (S.red2[0] + S.red2[1] + S.red2[2] + S.red2[3]) * (1.f / 128.f) - mean2 * mean2;
  if (h == 0) S.yl[d] = (o - mean2) * rsqrtf(var2 + LN_EPS_) * p.lnsg[d] + p.lnsb[d];
  __syncthreads();
  float q = halfDot(p.Wq + (size_t)d * 128, S.yl, h);
  q += __shfl_xor(q, 1, 64);
  if (h == 0) S.xl[d] = q;
  __syncthreads();
  float qv = waveReduceSum(h == 0 ? q * p.f_b2[d] : 0.f);
  if (lane == 0) S.red[w] = qv;
  float qf = halfDot(FW2T + (size_t)d * 128, S.xl, h);
  qf += __shfl_xor(qf, 1, 64);
  __syncthreads();
  if (t == 0) ws[OFF_QB + bs] = (S.red[0] + S.red[1] + S.red[2] + S.red[3]) * SCALE;
  if (h == 0) {
    float offd = -(sp0 * ws[OFF_GFD + d * 2 + 0] + sp1 * ws[OFF_GFD + d * 2 + 1]);
    ws[OFF_OQ + (bs * 128 + d) * 2 + 0] = offd;
    ws[OFF_OQ + (bs * 128 + d) * 2 + 1] = qf * SCALE;
  }
}

__device__ void doOut(int blk, const IterParams& p) {
  int i = blk * 256 + threadIdx.x;
  if (i < 8704) {
    float v;
    if (i < 8192) v = p.ws[OFF_SLOTS + i];
    else if (i < 8320) v = p.ws[OFF_SP + i - 8192];
    else if (i < 8576) v = p.S_r[i - 8320];
    else v = p.S_s[i - 8576];
    p.out[i] = v;
  }
}

// ---------------- cooperative mega-kernel (256 blocks = 1/CU, safe) ----------------
__global__ __launch_bounds__(256, 2) void kIter(IterParams p) {
  cg::grid_group grid = cg::this_grid();
  __shared__ __align__(16) char smraw[SM_BYTES];
  int blk = blockIdx.x;

  if (blk < 64) doQ(blk, p, *reinterpret_cast<QSm*>(smraw));
  grid.sync();
  for (int it = 0; it < 3; ++it) {
    doAttnPair(blk, p.ws, *reinterpret_cast<AttnSm*>(smraw));
    grid.sync();
    if (blk < 64) doCQ(blk, p, *reinterpret_cast<CQSm*>(smraw));
    grid.sync();
  }
  doOut(blk, p);
}

// ---------------- discrete fallback wrappers (same device code) ----------------
__global__ __launch_bounds__(256) void kQF(IterParams p) {
  __shared__ __align__(16) char smraw[sizeof(QSm)];
  doQ(blockIdx.x, p, *reinterpret_cast<QSm*>(smraw));
}
__global__ __launch_bounds__(256) void kAttnF(IterParams p) {
  __shared__ __align__(16) char smraw[SM_BYTES];
  doAttnPair(blockIdx.x, p.ws, *reinterpret_cast<AttnSm*>(smraw));
}
__global__ __launch_bounds__(256) void kCQF(IterParams p) {
  __shared__ __align__(16) char smraw[sizeof(CQSm)];
  doCQ(blockIdx.x, p, *reinterpret_cast<CQSm*>(smraw));
}
__global__ __launch_bounds__(256) void kOutF(IterParams p) {
  doOut(blockIdx.x, p);
}

extern "C" void kernel_launch(void* const* d_in, const int* in_sizes, int n_in,
                              void* d_out, int out_size, void* d_ws, size_t ws_size,
                              hipStream_t stream) {
  const float* inputs     = (const float*)d_in[0];
  const float* slots_init = (const float*)d_in[1];
  const float* S_p0       = (const float*)d_in[2];
  const float* S_s        = (const float*)d_in[3];
  const float* S_r        = (const float*)d_in[4];
  const float* Wq   = (const float*)d_in[5];
  const float* Wk   = (const float*)d_in[6];
  const float* Wv   = (const float*)d_in[7];
  const float* g_w  = (const float*)d_in[8];
  const float* g_b  = (const float*)d_in[9];
  const float* f_w1 = (const float*)d_in[10];
  const float* f_b1 = (const float*)d_in[11];
  const float* f_w2 = (const float*)d_in[12];
  const float* f_b2 = (const float*)d_in[13];
  const float* gwih = (const float*)d_in[14];
  const float* gwhh = (const float*)d_in[15];
  const float* gbih = (const float*)d_in[16];
  const float* gbhh = (const float*)d_in[17];
  const float* mw1  = (const float*)d_in[18];
  const float* mb1  = (const float*)d_in[19];
  const float* mw2  = (const float*)d_in[20];
  const float* mb2  = (const float*)d_in[21];
  const float* lnsg = (const float*)d_in[22];
  const float* lnsb = (const float*)d_in[23];
  const float* lnpg = (const float*)d_in[24];
  const float* lnpb = (const float*)d_in[25];
  float* ws  = (float*)d_ws;
  float* out = (float*)d_out;

  hipMemcpyAsync(ws + OFF_SLOTS, slots_init, 8192 * sizeof(float),
                 hipMemcpyDeviceToDevice, stream);
  hipMemcpyAsync(ws + OFF_SP, S_p0, 128 * sizeof(float),
                 hipMemcpyDeviceToDevice, stream);
  kFold<<<131, 256, 0, stream>>>(f_w1, Wk, Wv, g_w, g_b, f_b1, f_w2, ws);
  kBase<<<dim3(256, 2), 256, 0, stream>>>(inputs, ws);

  IterParams P;
  P.Wq = Wq; P.f_w2 = f_w2; P.f_b2 = f_b2;
  P.wih = gwih; P.whh = gwhh; P.bih = gbih; P.bhh = gbhh;
  P.mw1 = mw1; P.mb1 = mb1; P.mw2 = mw2; P.mb2 = mb2;
  P.lnpg = lnpg; P.lnpb = lnpb; P.lnsg = lnsg; P.lnsb = lnsb;
  P.S_r = S_r; P.S_s = S_s;
  P.ws = ws; P.out = out;

  int dev = 0, coop = 0;
  hipGetDevice(&dev);
  hipDeviceGetAttribute(&coop, hipDeviceAttributeCooperativeLaunch, dev);
  hipError_t st = hipErrorUnknown;
  if (coop) {
    void* args[] = { &P };
    st = hipLaunchCooperativeKernel((const void*)kIter, dim3(256), dim3(256),
                                    args, 0, stream);
  }
  if (st != hipSuccess) {
    kQF<<<64, 256, 0, stream>>>(P);
    for (int it = 0; it < 3; ++it) {
      kAttnF<<<256, 256, 0, stream>>>(P);
      kCQF<<<64, 256, 0, stream>>>(P);
    }
    kOutF<<<34, 256, 0, stream>>>(P);
  }
}